// Round 4
// baseline (318.948 us; speedup 1.0000x reference)
//
#include <hip/hip_runtime.h>
#include <hip/hip_bf16.h>

typedef unsigned short u16;
typedef __attribute__((ext_vector_type(8))) short bf16x8;
typedef __attribute__((ext_vector_type(4))) float f32x4;

#define B_  4
#define T_  2048
#define C_  1024
#define H_  16
#define DH_ 64
#define M_  (B_*T_)   // 8192

// async global->LDS, 16B per lane; LDS dest = wave-uniform base + lane*16
#define GLDS16(g, l) __builtin_amdgcn_global_load_lds( \
    (const __attribute__((address_space(1))) void*)(g), \
    (__attribute__((address_space(3))) void*)(l), 16, 0, 0)

__device__ __forceinline__ u16 f2b(float f) {
  union { __hip_bfloat16 h; u16 u; } cv;
  cv.h = __float2bfloat16(f);
  return cv.u;
}

// ---------------- fp32 -> bf16 cast, 4 elems/thread ----------------
__global__ void cast_bf16_kernel(const float* __restrict__ in, u16* __restrict__ out, int n) {
  int i = (blockIdx.x * blockDim.x + threadIdx.x) * 4;
  if (i >= n) return;
  float4 v = *(const float4*)(in + i);
  unsigned lo = (unsigned)f2b(v.x) | ((unsigned)f2b(v.y) << 16);
  unsigned hi = (unsigned)f2b(v.z) | ((unsigned)f2b(v.w) << 16);
  uint2 p; p.x = lo; p.y = hi;
  *(uint2*)(out + i) = p;
}

// three 1M-element weight casts in one launch (grid 3*1024 blocks)
__global__ void cast_w3_kernel(const float* __restrict__ w0, const float* __restrict__ w1,
                               const float* __restrict__ w2, u16* __restrict__ o0,
                               u16* __restrict__ o1, u16* __restrict__ o2) {
  int bid = blockIdx.x;
  const float* src = (bid < 1024) ? w0 : (bid < 2048) ? w1 : w2;
  u16*         dst = (bid < 1024) ? o0 : (bid < 2048) ? o1 : o2;
  int i = (((bid & 1023) * blockDim.x) + threadIdx.x) * 4;
  float4 v = *(const float4*)(src + i);
  unsigned lo = (unsigned)f2b(v.x) | ((unsigned)f2b(v.y) << 16);
  unsigned hi = (unsigned)f2b(v.z) | ((unsigned)f2b(v.w) << 16);
  uint2 p; p.x = lo; p.y = hi;
  *(uint2*)(dst + i) = p;
}

// ---------------- GEMM: C[m,n] = sum_k A[m,k] * B[n,k]  (B row-major [N,K]) ----------------
// m97-style: 128x128 tile, BK=32, global_load_lds width-16 staging, unpadded LDS (64B rows).
// mode 0: bf16 scatter; N=2048 = [Wq;Wv]: Q-half -> [B,H,T,Dh], V-half -> Vt [B,H,Dh,T]
// mode 1: fp32 row-major [M,1024]
__global__ __launch_bounds__(256) void gemm_bt_kernel(
    const u16* __restrict__ A, const u16* __restrict__ Bm,
    void* __restrict__ Cout, int mode)
{
  constexpr int K = 1024;
  __shared__ __align__(16) u16 As[128 * 32];
  __shared__ __align__(16) u16 Bs[128 * 32];

  const int tid  = threadIdx.x;
  const int wave = tid >> 6, lane = tid & 63;
  const int quad = lane >> 4, l15 = lane & 15;
  const int wm = (wave >> 1) * 64, wn = (wave & 1) * 64;
  const int tm = blockIdx.x * 128, tn = blockIdx.y * 128;

  const int c0 = wave * 128 + lane;
  const int c1 = c0 + 64;
  const int r0 = c0 >> 2, o0 = (c0 & 3) * 8;
  const int r1 = c1 >> 2, o1 = (c1 & 3) * 8;
  u16* ldsA0 = &As[wave * 1024];
  u16* ldsA1 = &As[wave * 1024 + 512];
  u16* ldsB0 = &Bs[wave * 1024];
  u16* ldsB1 = &Bs[wave * 1024 + 512];

  f32x4 acc[4][4] = {};

  for (int k0 = 0; k0 < K; k0 += 32) {
    GLDS16(A  + (size_t)(tm + r0) * K + k0 + o0, ldsA0);
    GLDS16(A  + (size_t)(tm + r1) * K + k0 + o1, ldsA1);
    GLDS16(Bm + (size_t)(tn + r0) * K + k0 + o0, ldsB0);
    GLDS16(Bm + (size_t)(tn + r1) * K + k0 + o1, ldsB1);
    __syncthreads();

    bf16x8 af[4], bfr[4];
#pragma unroll
    for (int t = 0; t < 4; t++) {
      af[t]  = *(const bf16x8*)(&As[(wm + t * 16 + l15) * 32 + quad * 8]);
      bfr[t] = *(const bf16x8*)(&Bs[(wn + t * 16 + l15) * 32 + quad * 8]);
    }
#pragma unroll
    for (int mt = 0; mt < 4; mt++)
#pragma unroll
      for (int nt = 0; nt < 4; nt++)
        acc[mt][nt] = __builtin_amdgcn_mfma_f32_16x16x32_bf16(af[mt], bfr[nt], acc[mt][nt], 0, 0, 0);
    __syncthreads();
  }

  if (mode == 0) {
    u16* out = (u16*)Cout;
    if (tn < 1024) {
#pragma unroll
      for (int mt = 0; mt < 4; mt++)
#pragma unroll
        for (int nt = 0; nt < 4; nt++)
#pragma unroll
          for (int r = 0; r < 4; r++) {
            int gm = tm + wm + mt * 16 + quad * 4 + r;
            int gn = tn + wn + nt * 16 + l15;
            int b = gm >> 11, t = gm & 2047;
            int h = gn >> 6, d = gn & 63;
            out[((size_t)((b * 16 + h) * 2048 + t) << 6) + d] = f2b(acc[mt][nt][r]);
          }
    } else {
      // V half -> Vt [B,H,Dh,T] (fused transpose)
#pragma unroll
      for (int mt = 0; mt < 4; mt++)
#pragma unroll
        for (int nt = 0; nt < 4; nt++) {
          int gm0 = tm + wm + mt * 16 + quad * 4;
          int gn  = tn - 1024 + wn + nt * 16 + l15;
          int b = gm0 >> 11, t0 = gm0 & 2047;
          int h = gn >> 6, d = gn & 63;
          alignas(8) u16 tmp[4];
#pragma unroll
          for (int r = 0; r < 4; r++) tmp[r] = f2b(acc[mt][nt][r]);
          *(ushort4*)(out + 8388608 + (((size_t)(b * 16 + h) * 64 + d) << 11) + t0)
              = *(const ushort4*)tmp;
        }
    }
  } else {
    float* out = (float*)Cout;
#pragma unroll
    for (int mt = 0; mt < 4; mt++)
#pragma unroll
      for (int nt = 0; nt < 4; nt++)
#pragma unroll
        for (int r = 0; r < 4; r++) {
          int gm = tm + wm + mt * 16 + quad * 4 + r;
          int gn = tn + wn + nt * 16 + l15;
          out[(size_t)gm * 1024 + gn] = acc[mt][nt][r];
        }
  }
}

// ---------------- causal flash attention, K==Q (reference bug), bf16 MFMA ----------------
// One wave per (bh, 32-row q-tile): 4096 single-wave blocks, longest-first (LPT),
// XCD-packed bh (bits 0-5). Barrier-free, fixed-max softmax. 3 waves/SIMD target.
__global__ __launch_bounds__(64, 3) void attn_kernel(
    const u16* __restrict__ Q, const u16* __restrict__ Vt, u16* __restrict__ AO)
{
  constexpr int LDP = 72;
  __shared__ __align__(16) u16 Ps[32 * LDP];

  const int lane = threadIdx.x;
  const int quad = lane >> 4, l15 = lane & 15;
  const int bid  = blockIdx.x;
  // bits 0-5: bh, XCD-packed (bid%8 -> XCD, each XCD owns 8 bh = 4MB K+V = its L2)
  const int bh = (bid & 7) * 8 + ((bid >> 3) & 7);
  const int i  = 63 - (bid >> 6);   // q-tile, longest-first
  const int b = bh >> 4, h = bh & 15;
  const u16* Qbh = Q  + (size_t)bh * (T_ * DH_);
  const u16* Vbh = Vt + (size_t)bh * (DH_ * T_);
  const int q0  = i * 32;
  const int nkb = (i >> 1) + 1;

  const float C1 = 0.18033688f;    // log2(e)/sqrt(64)
  const float C2 = -28.8539008f;   // -20*log2(e)  (fixed max M=20, shift-invariant)

  bf16x8 qf[2][2];
#pragma unroll
  for (int mt = 0; mt < 2; mt++)
#pragma unroll
    for (int ks = 0; ks < 2; ks++)
      qf[mt][ks] = *(const bf16x8*)(Qbh + (size_t)(q0 + mt * 16 + l15) * DH_ + ks * 32 + quad * 8);

  f32x4 o[2][4] = {};
  float lsum[2][4] = {};

  for (int kb = 0; kb < nkb; kb++) {
    const int k0 = kb * 64;

    // K fragments (dh-contiguous = natural layout)
    bf16x8 kf[4][2];
#pragma unroll
    for (int nt = 0; nt < 4; nt++)
#pragma unroll
      for (int ks = 0; ks < 2; ks++)
        kf[nt][ks] = *(const bf16x8*)(Qbh + (size_t)(k0 + nt * 16 + l15) * DH_ + ks * 32 + quad * 8);

    // S = Q K^T
    f32x4 s[2][4] = {};
#pragma unroll
    for (int ks = 0; ks < 2; ks++)
#pragma unroll
      for (int nt = 0; nt < 4; nt++)
#pragma unroll
        for (int mt = 0; mt < 2; mt++)
          s[mt][nt] = __builtin_amdgcn_mfma_f32_16x16x32_bf16(qf[mt][ks], kf[nt][ks], s[mt][nt], 0, 0, 0);

    // V fragments issued here: kf dead, vf consumed ~400 cyc later after softmax
    bf16x8 vf[4][2];
#pragma unroll
    for (int dt = 0; dt < 4; dt++)
#pragma unroll
      for (int ks = 0; ks < 2; ks++)
        vf[dt][ks] = *(const bf16x8*)(Vbh + (size_t)(dt * 16 + l15) * T_ + k0 + ks * 32 + quad * 8);

    // fixed-max softmax: p = exp2(s*C1 + C2); per-lane partial row sums
    const bool diag = (kb == nkb - 1);
#pragma unroll
    for (int mt = 0; mt < 2; mt++)
#pragma unroll
      for (int nt = 0; nt < 4; nt++)
#pragma unroll
        for (int r = 0; r < 4; r++) {
          float p = exp2f(s[mt][nt][r] * C1 + C2);
          if (diag) {
            int qg = q0 + mt * 16 + quad * 4 + r;
            int kg = k0 + nt * 16 + l15;
            p = (kg <= qg) ? p : 0.0f;
          }
          lsum[mt][r] += p;
          Ps[(mt * 16 + quad * 4 + r) * LDP + nt * 16 + l15] = f2b(p);
        }

    // O += P V  (P C-layout -> A-layout via LDS; single wave -> no barrier)
#pragma unroll
    for (int ks2 = 0; ks2 < 2; ks2++) {
      bf16x8 pf[2];
#pragma unroll
      for (int mt = 0; mt < 2; mt++)
        pf[mt] = *(const bf16x8*)(&Ps[(mt * 16 + l15) * LDP + ks2 * 32 + quad * 8]);
#pragma unroll
      for (int dt = 0; dt < 4; dt++)
#pragma unroll
        for (int mt = 0; mt < 2; mt++)
          o[mt][dt] = __builtin_amdgcn_mfma_f32_16x16x32_bf16(pf[mt], vf[dt][ks2], o[mt][dt], 0, 0, 0);
    }
  }

  // epilogue: reduce row sums across 16-lane col groups, normalize, store
#pragma unroll
  for (int mt = 0; mt < 2; mt++)
#pragma unroll
    for (int r = 0; r < 4; r++) {
      float v = lsum[mt][r];
#pragma unroll
      for (int off = 1; off < 16; off <<= 1) v += __shfl_xor(v, off, 64);
      float rl = 1.0f / v;
      int t = q0 + mt * 16 + quad * 4 + r;
#pragma unroll
      for (int dt = 0; dt < 4; dt++)
        AO[((size_t)(b * T_ + t)) * C_ + h * DH_ + dt * 16 + l15] = f2b(o[mt][dt][r] * rl);
    }
}

extern "C" void kernel_launch(void* const* d_in, const int* in_sizes, int n_in,
                              void* d_out, int out_size, void* d_ws, size_t ws_size,
                              hipStream_t stream) {
  (void)in_sizes; (void)n_in; (void)out_size; (void)ws_size;
  const float* x  = (const float*)d_in[0];
  const float* Wq = (const float*)d_in[1];
  // d_in[2] = W_k unused (reference bug: K uses W_q)
  const float* Wv = (const float*)d_in[3];
  const float* Wo = (const float*)d_in[4];

  // workspace (u16 elems); AO reuses Xb slot (dead after gemm1)
  u16* Xb  = (u16*)d_ws;            // 8388608 : x bf16; later AO [B,T,C]
  u16* AOw = Xb;
  u16* Wqb = Xb  + 8388608;         // 1048576
  u16* Wvb = Wqb + 1048576;         // 1048576 (adjacent -> fused N=2048 GEMM)
  u16* Wob = Wvb + 1048576;         // 1048576
  u16* Qw  = Wob + 1048576;         // 8388608 : Q [B,H,T,Dh]
  u16* Vtw = Qw  + 8388608;         // 8388608 : Vt [B,H,Dh,T] (gemm1 writes directly)
  // total 54,525,952 bytes

  cast_bf16_kernel<<<8192, 256, 0, stream>>>(x, Xb, 8388608);
  cast_w3_kernel<<<3072, 256, 0, stream>>>(Wq, Wv, Wo, Wqb, Wvb, Wob);

  // fused Q+V projection; V half written pre-transposed (Vt base = Qw + 8388608)
  gemm_bt_kernel<<<dim3(64, 16), 256, 0, stream>>>(Xb, Wqb, (void*)Qw, 0);

  attn_kernel<<<4096, 64, 0, stream>>>(Qw, Vtw, AOw);

  gemm_bt_kernel<<<dim3(64, 8), 256, 0, stream>>>(AOw, Wob, d_out, 1);
}

// Round 5
// 251.065 us; speedup vs baseline: 1.2704x; 1.2704x over previous
//
#include <hip/hip_runtime.h>
#include <hip/hip_bf16.h>

typedef unsigned short u16;
typedef __attribute__((ext_vector_type(8))) short bf16x8;
typedef __attribute__((ext_vector_type(4))) float f32x4;

#define B_  4
#define T_  2048
#define C_  1024
#define H_  16
#define DH_ 64
#define M_  (B_*T_)   // 8192

// async global->LDS, 16B per lane; LDS dest = wave-uniform base + lane*16
#define GLDS16(g, l) __builtin_amdgcn_global_load_lds( \
    (const __attribute__((address_space(1))) void*)(g), \
    (__attribute__((address_space(3))) void*)(l), 16, 0, 0)

__device__ __forceinline__ u16 f2b(float f) {
  union { __hip_bfloat16 h; u16 u; } cv;
  cv.h = __float2bfloat16(f);
  return cv.u;
}

// ---------------- fp32 -> bf16 cast, 4 elems/thread ----------------
__global__ void cast_bf16_kernel(const float* __restrict__ in, u16* __restrict__ out, int n) {
  int i = (blockIdx.x * blockDim.x + threadIdx.x) * 4;
  if (i >= n) return;
  float4 v = *(const float4*)(in + i);
  unsigned lo = (unsigned)f2b(v.x) | ((unsigned)f2b(v.y) << 16);
  unsigned hi = (unsigned)f2b(v.z) | ((unsigned)f2b(v.w) << 16);
  uint2 p; p.x = lo; p.y = hi;
  *(uint2*)(out + i) = p;
}

// three 1M-element weight casts in one launch (grid 3*1024 blocks)
__global__ void cast_w3_kernel(const float* __restrict__ w0, const float* __restrict__ w1,
                               const float* __restrict__ w2, u16* __restrict__ o0,
                               u16* __restrict__ o1, u16* __restrict__ o2) {
  int bid = blockIdx.x;
  const float* src = (bid < 1024) ? w0 : (bid < 2048) ? w1 : w2;
  u16*         dst = (bid < 1024) ? o0 : (bid < 2048) ? o1 : o2;
  int i = (((bid & 1023) * blockDim.x) + threadIdx.x) * 4;
  float4 v = *(const float4*)(src + i);
  unsigned lo = (unsigned)f2b(v.x) | ((unsigned)f2b(v.y) << 16);
  unsigned hi = (unsigned)f2b(v.z) | ((unsigned)f2b(v.w) << 16);
  uint2 p; p.x = lo; p.y = hi;
  *(uint2*)(dst + i) = p;
}

// ---------------- GEMM: C[m,n] = sum_k A[m,k] * B[n,k]  (B row-major [N,K]) ----------------
// m97-style: 128x128 tile, BK=32, global_load_lds width-16 staging, unpadded LDS (64B rows).
// mode 0: bf16 scatter; N=2048 = [Wq;Wv]: Q-half -> [B,H,T,Dh], V-half -> Vt [B,H,Dh,T]
// mode 1: fp32 row-major [M,1024]
__global__ __launch_bounds__(256) void gemm_bt_kernel(
    const u16* __restrict__ A, const u16* __restrict__ Bm,
    void* __restrict__ Cout, int mode)
{
  constexpr int K = 1024;
  __shared__ __align__(16) u16 As[128 * 32];
  __shared__ __align__(16) u16 Bs[128 * 32];

  const int tid  = threadIdx.x;
  const int wave = tid >> 6, lane = tid & 63;
  const int quad = lane >> 4, l15 = lane & 15;
  const int wm = (wave >> 1) * 64, wn = (wave & 1) * 64;
  const int tm = blockIdx.x * 128, tn = blockIdx.y * 128;

  const int c0 = wave * 128 + lane;
  const int c1 = c0 + 64;
  const int r0 = c0 >> 2, o0 = (c0 & 3) * 8;
  const int r1 = c1 >> 2, o1 = (c1 & 3) * 8;
  u16* ldsA0 = &As[wave * 1024];
  u16* ldsA1 = &As[wave * 1024 + 512];
  u16* ldsB0 = &Bs[wave * 1024];
  u16* ldsB1 = &Bs[wave * 1024 + 512];

  f32x4 acc[4][4] = {};

  for (int k0 = 0; k0 < K; k0 += 32) {
    GLDS16(A  + (size_t)(tm + r0) * K + k0 + o0, ldsA0);
    GLDS16(A  + (size_t)(tm + r1) * K + k0 + o1, ldsA1);
    GLDS16(Bm + (size_t)(tn + r0) * K + k0 + o0, ldsB0);
    GLDS16(Bm + (size_t)(tn + r1) * K + k0 + o1, ldsB1);
    __syncthreads();

    bf16x8 af[4], bfr[4];
#pragma unroll
    for (int t = 0; t < 4; t++) {
      af[t]  = *(const bf16x8*)(&As[(wm + t * 16 + l15) * 32 + quad * 8]);
      bfr[t] = *(const bf16x8*)(&Bs[(wn + t * 16 + l15) * 32 + quad * 8]);
    }
#pragma unroll
    for (int mt = 0; mt < 4; mt++)
#pragma unroll
      for (int nt = 0; nt < 4; nt++)
        acc[mt][nt] = __builtin_amdgcn_mfma_f32_16x16x32_bf16(af[mt], bfr[nt], acc[mt][nt], 0, 0, 0);
    __syncthreads();
  }

  if (mode == 0) {
    u16* out = (u16*)Cout;
    if (tn < 1024) {
#pragma unroll
      for (int mt = 0; mt < 4; mt++)
#pragma unroll
        for (int nt = 0; nt < 4; nt++)
#pragma unroll
          for (int r = 0; r < 4; r++) {
            int gm = tm + wm + mt * 16 + quad * 4 + r;
            int gn = tn + wn + nt * 16 + l15;
            int b = gm >> 11, t = gm & 2047;
            int h = gn >> 6, d = gn & 63;
            out[((size_t)((b * 16 + h) * 2048 + t) << 6) + d] = f2b(acc[mt][nt][r]);
          }
    } else {
      // V half -> Vt [B,H,Dh,T] (fused transpose)
#pragma unroll
      for (int mt = 0; mt < 4; mt++)
#pragma unroll
        for (int nt = 0; nt < 4; nt++) {
          int gm0 = tm + wm + mt * 16 + quad * 4;
          int gn  = tn - 1024 + wn + nt * 16 + l15;
          int b = gm0 >> 11, t0 = gm0 & 2047;
          int h = gn >> 6, d = gn & 63;
          alignas(8) u16 tmp[4];
#pragma unroll
          for (int r = 0; r < 4; r++) tmp[r] = f2b(acc[mt][nt][r]);
          *(ushort4*)(out + 8388608 + (((size_t)(b * 16 + h) * 64 + d) << 11) + t0)
              = *(const ushort4*)tmp;
        }
    }
  } else {
    float* out = (float*)Cout;
#pragma unroll
    for (int mt = 0; mt < 4; mt++)
#pragma unroll
      for (int nt = 0; nt < 4; nt++)
#pragma unroll
        for (int r = 0; r < 4; r++) {
          int gm = tm + wm + mt * 16 + quad * 4 + r;
          int gn = tn + wn + nt * 16 + l15;
          out[(size_t)gm * 1024 + gn] = acc[mt][nt][r];
        }
  }
}

// ---------------- causal flash attention, K==Q (reference bug), bf16 MFMA ----------------
// m97-skeleton: 4-wave block owns 128 q-rows; K-tile + Vt-tile staged once per block via
// global_load_lds width-16 into m97-layout LDS ([ks][row][32], 64B rows); fragments via
// ds_read_b128. Fixed-max softmax with raw v_exp_f32. XCD-packed bh; q-tile map gives every
// CU's 4 resident blocks exactly 68 tile-units ({32+18+16+2} etc). 34.8KB LDS -> 4 blk/CU.
__global__ __launch_bounds__(256, 4) void attn_kernel(
    const u16* __restrict__ Q, const u16* __restrict__ Vt, u16* __restrict__ AO)
{
  constexpr int LDP = 72;
  __shared__ __align__(16) u16 Ks[4096];        // [ks][key 64][32]   8KB
  __shared__ __align__(16) u16 Vs[4096];        // [ks2][d 64][32]    8KB
  __shared__ __align__(16) u16 Ps[4][32 * LDP]; // per-wave P         18KB

  const int tid  = threadIdx.x;
  const int wave = tid >> 6, lane = tid & 63;
  const int quad = lane >> 4, l15 = lane & 15;
  const int bid  = blockIdx.x;
  // bits 0-5: bh, XCD-packed (bid%8 -> XCD; each XCD owns 8 bh = 4MB K+V = its L2)
  const int bh = (bid & 7) * 8 + ((bid >> 3) & 7);
  const int m  = bid >> 6;                       // 0..15
  // balanced-LPT q-tile map: CU's resident set {m, m+4, m+8, m+12} sums to 68 tiles
  const int i  = (m & 4) ? ((m & 8) ? m - 12 : m + 4) : 15 - m;
  const int b = bh >> 4, h = bh & 15;
  const u16* Qbh = Q  + (size_t)bh * (T_ * DH_);
  const u16* Vbh = Vt + (size_t)bh * (DH_ * T_);
  const int q0w   = i * 128 + wave * 32;   // wave's first q-row
  const int qmaxw = q0w + 31;
  const int nkb   = 2 * i + 2;             // block-level k-tiles (64 keys each)
  u16* myP = &Ps[wave][0];

  // staging: 256 threads x (2 K-chunks + 2 V-chunks) of 16B
  const int srow = tid >> 2, soff = (tid & 3) * 8;
  u16* ldsK0 = &Ks[wave * 512];
  u16* ldsK1 = &Ks[2048 + wave * 512];
  u16* ldsV0 = &Vs[wave * 512];
  u16* ldsV1 = &Vs[2048 + wave * 512];

  const float C1 = 0.18033688f;    // log2(e)/sqrt(64)
  const float C2 = -28.8539008f;   // -20*log2(e)  (fixed max M=20, shift-invariant)

  // Q fragments: once per block, direct global
  bf16x8 qf[2][2];
#pragma unroll
  for (int mt = 0; mt < 2; mt++)
#pragma unroll
    for (int ks = 0; ks < 2; ks++)
      qf[mt][ks] = *(const bf16x8*)(Qbh + (size_t)(q0w + mt * 16 + l15) * DH_ + ks * 32 + quad * 8);

  f32x4 o[2][4] = {};
  float lsum[2][4] = {};

  for (int kb = 0; kb < nkb; kb++) {
    const int k0 = kb * 64;
    // stage K-tile (rows k0.., dh-halves) and Vt-tile (rows d, key-halves)
    GLDS16(Qbh + (size_t)(k0 + srow) * DH_ + soff,      ldsK0);
    GLDS16(Qbh + (size_t)(k0 + srow) * DH_ + 32 + soff, ldsK1);
    GLDS16(Vbh + (size_t)srow * T_ + k0 + soff,         ldsV0);
    GLDS16(Vbh + (size_t)srow * T_ + k0 + 32 + soff,    ldsV1);
    __syncthreads();

    if (k0 <= qmaxw) {   // wave-uniform skip of fully-masked tiles
      // S = Q K^T
      f32x4 s[2][4] = {};
#pragma unroll
      for (int ks = 0; ks < 2; ks++)
#pragma unroll
        for (int nt = 0; nt < 4; nt++) {
          bf16x8 kf = *(const bf16x8*)(&Ks[ks * 2048 + (nt * 16 + l15) * 32 + quad * 8]);
#pragma unroll
          for (int mt = 0; mt < 2; mt++)
            s[mt][nt] = __builtin_amdgcn_mfma_f32_16x16x32_bf16(qf[mt][ks], kf, s[mt][nt], 0, 0, 0);
        }

      // fixed-max softmax: p = exp2(s*C1 + C2), raw v_exp_f32
      const bool diag = (k0 + 63 > q0w);
#pragma unroll
      for (int mt = 0; mt < 2; mt++)
#pragma unroll
        for (int nt = 0; nt < 4; nt++)
#pragma unroll
          for (int r = 0; r < 4; r++) {
            float p = __builtin_amdgcn_exp2f(s[mt][nt][r] * C1 + C2);
            if (diag) {
              int qg = q0w + mt * 16 + quad * 4 + r;
              int kg = k0 + nt * 16 + l15;
              p = (kg <= qg) ? p : 0.0f;
            }
            lsum[mt][r] += p;
            myP[(mt * 16 + quad * 4 + r) * LDP + nt * 16 + l15] = f2b(p);
          }

      // O += P V  (P C-layout -> A-layout via wave-private LDS)
#pragma unroll
      for (int ks2 = 0; ks2 < 2; ks2++) {
        bf16x8 pf[2];
#pragma unroll
        for (int mt = 0; mt < 2; mt++)
          pf[mt] = *(const bf16x8*)(&myP[(mt * 16 + l15) * LDP + ks2 * 32 + quad * 8]);
#pragma unroll
        for (int dt = 0; dt < 4; dt++) {
          bf16x8 vf = *(const bf16x8*)(&Vs[ks2 * 2048 + (dt * 16 + l15) * 32 + quad * 8]);
#pragma unroll
          for (int mt = 0; mt < 2; mt++)
            o[mt][dt] = __builtin_amdgcn_mfma_f32_16x16x32_bf16(pf[mt], vf, o[mt][dt], 0, 0, 0);
        }
      }
    }
    __syncthreads();
  }

  // epilogue: reduce row sums across 16-lane col groups, normalize, store
#pragma unroll
  for (int mt = 0; mt < 2; mt++)
#pragma unroll
    for (int r = 0; r < 4; r++) {
      float v = lsum[mt][r];
#pragma unroll
      for (int off = 1; off < 16; off <<= 1) v += __shfl_xor(v, off, 64);
      float rl = 1.0f / v;
      int t = q0w + mt * 16 + quad * 4 + r;
#pragma unroll
      for (int dt = 0; dt < 4; dt++)
        AO[((size_t)(b * T_ + t)) * C_ + h * DH_ + dt * 16 + l15] = f2b(o[mt][dt][r] * rl);
    }
}

extern "C" void kernel_launch(void* const* d_in, const int* in_sizes, int n_in,
                              void* d_out, int out_size, void* d_ws, size_t ws_size,
                              hipStream_t stream) {
  (void)in_sizes; (void)n_in; (void)out_size; (void)ws_size;
  const float* x  = (const float*)d_in[0];
  const float* Wq = (const float*)d_in[1];
  // d_in[2] = W_k unused (reference bug: K uses W_q)
  const float* Wv = (const float*)d_in[3];
  const float* Wo = (const float*)d_in[4];

  // workspace (u16 elems); AO reuses Xb slot (dead after gemm1)
  u16* Xb  = (u16*)d_ws;            // 8388608 : x bf16; later AO [B,T,C]
  u16* AOw = Xb;
  u16* Wqb = Xb  + 8388608;         // 1048576
  u16* Wvb = Wqb + 1048576;         // 1048576 (adjacent -> fused N=2048 GEMM)
  u16* Wob = Wvb + 1048576;         // 1048576
  u16* Qw  = Wob + 1048576;         // 8388608 : Q [B,H,T,Dh]
  u16* Vtw = Qw  + 8388608;         // 8388608 : Vt [B,H,Dh,T] (gemm1 writes directly)
  // total 54,525,952 bytes

  cast_bf16_kernel<<<8192, 256, 0, stream>>>(x, Xb, 8388608);
  cast_w3_kernel<<<3072, 256, 0, stream>>>(Wq, Wv, Wo, Wqb, Wvb, Wob);

  // fused Q+V projection; V half written pre-transposed (Vt base = Qw + 8388608)
  gemm_bt_kernel<<<dim3(64, 16), 256, 0, stream>>>(Xb, Wqb, (void*)Qw, 0);

  attn_kernel<<<1024, 256, 0, stream>>>(Qw, Vtw, AOw);

  gemm_bt_kernel<<<dim3(64, 8), 256, 0, stream>>>(AOw, Wob, d_out, 1);
}

// Round 6
// 235.033 us; speedup vs baseline: 1.3570x; 1.0682x over previous
//
#include <hip/hip_runtime.h>
#include <hip/hip_bf16.h>

typedef unsigned short u16;
typedef __attribute__((ext_vector_type(8))) short bf16x8;
typedef __attribute__((ext_vector_type(4))) float f32x4;

#define B_  4
#define T_  2048
#define C_  1024
#define H_  16
#define DH_ 64
#define M_  (B_*T_)   // 8192

// async global->LDS, 16B per lane; LDS dest = wave-uniform base + lane*16
#define GLDS16(g, l) __builtin_amdgcn_global_load_lds( \
    (const __attribute__((address_space(1))) void*)(g), \
    (__attribute__((address_space(3))) void*)(l), 16, 0, 0)

__device__ __forceinline__ u16 f2b(float f) {
  union { __hip_bfloat16 h; u16 u; } cv;
  cv.h = __float2bfloat16(f);
  return cv.u;
}

// ---------------- all fp32 -> bf16 casts in one launch ----------------
// grid 11264: [0,8192) = x (8M elems), [8192,11264) = 3 weights (1M each)
__global__ void cast_all_kernel(const float* __restrict__ x,  const float* __restrict__ w0,
                                const float* __restrict__ w1, const float* __restrict__ w2,
                                u16* __restrict__ xo, u16* __restrict__ o0,
                                u16* __restrict__ o1, u16* __restrict__ o2) {
  int bid = blockIdx.x;
  const float* src; u16* dst; int blk;
  if (bid < 8192) { src = x; dst = xo; blk = bid; }
  else {
    int k = bid - 8192, w = k >> 10;
    src = (w == 0) ? w0 : (w == 1) ? w1 : w2;
    dst = (w == 0) ? o0 : (w == 1) ? o1 : o2;
    blk = k & 1023;
  }
  int i = (blk * 256 + threadIdx.x) * 4;
  float4 v = *(const float4*)(src + i);
  unsigned lo = (unsigned)f2b(v.x) | ((unsigned)f2b(v.y) << 16);
  unsigned hi = (unsigned)f2b(v.z) | ((unsigned)f2b(v.w) << 16);
  uint2 p; p.x = lo; p.y = hi;
  *(uint2*)(dst + i) = p;
}

// ---------------- GEMM: C[m,n] = sum_k A[m,k] * B[n,k]  (B row-major [N,K]) ----------------
// 128x128 tile, BK=64 (16 staging rounds), global_load_lds width-16, XOR-swizzled LDS
// ([row][64], chunk ^= row&7 -> conflict-free b128 frag reads).
// mode 0: bf16 scatter; N=2048 = [Wq;Wv]: Q-half -> [B,H,T,Dh], V-half -> Vt [B,H,Dh,T]
// mode 1: fp32 row-major [M,1024]
__global__ __launch_bounds__(256) void gemm_bt_kernel(
    const u16* __restrict__ A, const u16* __restrict__ Bm,
    void* __restrict__ Cout, int mode)
{
  constexpr int K = 1024;
  __shared__ __align__(16) u16 As[128 * 64];   // 16KB, swizzled
  __shared__ __align__(16) u16 Bs[128 * 64];   // 16KB, swizzled

  const int tid  = threadIdx.x;
  const int wave = tid >> 6, lane = tid & 63;
  const int quad = lane >> 4, l15 = lane & 15;
  const int x7   = l15 & 7;
  const int wm = (wave >> 1) * 64, wn = (wave & 1) * 64;
  const int tm = blockIdx.x * 128, tn = blockIdx.y * 128;

  f32x4 acc[4][4] = {};

  for (int k0 = 0; k0 < K; k0 += 64) {
    // stage 128x64 A and B: 1024 chunks each, 4 per thread, fetch-side swizzle
#pragma unroll
    for (int it = 0; it < 4; it++) {
      int ch  = it * 256 + tid;
      int row = ch >> 3;
      int cc  = (ch & 7) ^ (row & 7);
      GLDS16(A  + (size_t)(tm + row) * K + k0 + cc * 8, &As[(it * 256 + wave * 64) * 8]);
      GLDS16(Bm + (size_t)(tn + row) * K + k0 + cc * 8, &Bs[(it * 256 + wave * 64) * 8]);
    }
    __syncthreads();

#pragma unroll
    for (int ks = 0; ks < 2; ks++) {
      bf16x8 af[4], bfr[4];
#pragma unroll
      for (int t = 0; t < 4; t++) {
        int co = ((ks * 4 + quad) ^ x7) * 8;
        af[t]  = *(const bf16x8*)(&As[(wm + t * 16 + l15) * 64 + co]);
        bfr[t] = *(const bf16x8*)(&Bs[(wn + t * 16 + l15) * 64 + co]);
      }
#pragma unroll
      for (int mt = 0; mt < 4; mt++)
#pragma unroll
        for (int nt = 0; nt < 4; nt++)
          acc[mt][nt] = __builtin_amdgcn_mfma_f32_16x16x32_bf16(af[mt], bfr[nt], acc[mt][nt], 0, 0, 0);
    }
    __syncthreads();
  }

  if (mode == 0) {
    u16* out = (u16*)Cout;
    if (tn < 1024) {
#pragma unroll
      for (int mt = 0; mt < 4; mt++)
#pragma unroll
        for (int nt = 0; nt < 4; nt++)
#pragma unroll
          for (int r = 0; r < 4; r++) {
            int gm = tm + wm + mt * 16 + quad * 4 + r;
            int gn = tn + wn + nt * 16 + l15;
            int b = gm >> 11, t = gm & 2047;
            int h = gn >> 6, d = gn & 63;
            out[((size_t)((b * 16 + h) * 2048 + t) << 6) + d] = f2b(acc[mt][nt][r]);
          }
    } else {
      // V half -> Vt [B,H,Dh,T] (fused transpose)
#pragma unroll
      for (int mt = 0; mt < 4; mt++)
#pragma unroll
        for (int nt = 0; nt < 4; nt++) {
          int gm0 = tm + wm + mt * 16 + quad * 4;
          int gn  = tn - 1024 + wn + nt * 16 + l15;
          int b = gm0 >> 11, t0 = gm0 & 2047;
          int h = gn >> 6, d = gn & 63;
          alignas(8) u16 tmp[4];
#pragma unroll
          for (int r = 0; r < 4; r++) tmp[r] = f2b(acc[mt][nt][r]);
          *(ushort4*)(out + 8388608 + (((size_t)(b * 16 + h) * 64 + d) << 11) + t0)
              = *(const ushort4*)tmp;
        }
    }
  } else {
    float* out = (float*)Cout;
#pragma unroll
    for (int mt = 0; mt < 4; mt++)
#pragma unroll
      for (int nt = 0; nt < 4; nt++)
#pragma unroll
        for (int r = 0; r < 4; r++) {
          int gm = tm + wm + mt * 16 + quad * 4 + r;
          int gn = tn + wn + nt * 16 + l15;
          out[(size_t)gm * 1024 + gn] = acc[mt][nt][r];
        }
  }
}

// ---------------- causal flash attention, K==Q (reference bug), bf16 MFMA ----------------
// m97-skeleton: 4-wave block owns 128 q-rows; K/Vt tiles staged per block via
// global_load_lds into XOR-swizzled [64][64] LDS; ds_read_b128 frags, conflict-free.
// Fixed-max softmax (raw v_exp_f32). XCD-packed bh; LPT q-tile map (4-resident sets sum 68).
__global__ __launch_bounds__(256, 4) void attn_kernel(
    const u16* __restrict__ Q, const u16* __restrict__ Vt, u16* __restrict__ AO)
{
  constexpr int LDP = 72;
  __shared__ __align__(16) u16 Ks[4096];        // [key 64][dh 64] swizzled, 8KB
  __shared__ __align__(16) u16 Vs[4096];        // [d 64][key 64] swizzled, 8KB
  __shared__ __align__(16) u16 Ps[4][32 * LDP]; // per-wave P, 18KB

  const int tid  = threadIdx.x;
  const int wave = tid >> 6, lane = tid & 63;
  const int quad = lane >> 4, l15 = lane & 15;
  const int x7   = l15 & 7;
  const int bid  = blockIdx.x;
  // bits 0-5: bh, XCD-packed (bid%8 -> XCD; each XCD owns 8 bh = 4MB K+V = its L2)
  const int bh = (bid & 7) * 8 + ((bid >> 3) & 7);
  const int m  = bid >> 6;                       // 0..15
  // balanced-LPT q-tile map: CU's resident set {m, m+4, m+8, m+12} sums to 68 tiles
  const int i  = (m & 4) ? ((m & 8) ? m - 12 : m + 4) : 15 - m;
  const int b = bh >> 4, h = bh & 15;
  const u16* Qbh = Q  + (size_t)bh * (T_ * DH_);
  const u16* Vbh = Vt + (size_t)bh * (DH_ * T_);
  const int q0w   = i * 128 + wave * 32;   // wave's first q-row
  const int qmaxw = q0w + 31;
  const int nkb   = 2 * i + 2;             // block-level k-tiles (64 keys each)
  u16* myP = &Ps[wave][0];

  const float C1 = 0.18033688f;    // log2(e)/sqrt(64)
  const float C2 = -28.8539008f;   // -20*log2(e)  (fixed max M=20, shift-invariant)

  // Q fragments: once per block, direct global
  bf16x8 qf[2][2];
#pragma unroll
  for (int mt = 0; mt < 2; mt++)
#pragma unroll
    for (int ks = 0; ks < 2; ks++)
      qf[mt][ks] = *(const bf16x8*)(Qbh + (size_t)(q0w + mt * 16 + l15) * DH_ + ks * 32 + quad * 8);

  f32x4 o[2][4] = {};
  float lsum[2][4] = {};

  for (int kb = 0; kb < nkb; kb++) {
    const int k0 = kb * 64;
    // stage K-tile [key][dh] and Vt-tile [d][key], fetch-side swizzle
#pragma unroll
    for (int it = 0; it < 2; it++) {
      int ch  = it * 256 + tid;
      int row = ch >> 3;
      int cc  = (ch & 7) ^ (row & 7);
      GLDS16(Qbh + (size_t)(k0 + row) * DH_ + cc * 8, &Ks[(it * 256 + wave * 64) * 8]);
      GLDS16(Vbh + (size_t)row * T_ + k0 + cc * 8,    &Vs[(it * 256 + wave * 64) * 8]);
    }
    __syncthreads();

    if (k0 <= qmaxw) {   // wave-uniform skip of fully-masked tiles
      // S = Q K^T
      f32x4 s[2][4] = {};
#pragma unroll
      for (int ks = 0; ks < 2; ks++)
#pragma unroll
        for (int nt = 0; nt < 4; nt++) {
          bf16x8 kf = *(const bf16x8*)(&Ks[(nt * 16 + l15) * 64 + (((ks * 4 + quad) ^ x7) * 8)]);
#pragma unroll
          for (int mt = 0; mt < 2; mt++)
            s[mt][nt] = __builtin_amdgcn_mfma_f32_16x16x32_bf16(qf[mt][ks], kf, s[mt][nt], 0, 0, 0);
        }

      // fixed-max softmax: p = exp2(s*C1 + C2), raw v_exp_f32
      const bool diag = (k0 + 63 > q0w);
#pragma unroll
      for (int mt = 0; mt < 2; mt++)
#pragma unroll
        for (int nt = 0; nt < 4; nt++)
#pragma unroll
          for (int r = 0; r < 4; r++) {
            float p = __builtin_amdgcn_exp2f(s[mt][nt][r] * C1 + C2);
            if (diag) {
              int qg = q0w + mt * 16 + quad * 4 + r;
              int kg = k0 + nt * 16 + l15;
              p = (kg <= qg) ? p : 0.0f;
            }
            lsum[mt][r] += p;
            myP[(mt * 16 + quad * 4 + r) * LDP + nt * 16 + l15] = f2b(p);
          }

      // O += P V  (P C-layout -> A-layout via wave-private LDS)
#pragma unroll
      for (int ks2 = 0; ks2 < 2; ks2++) {
        bf16x8 pf[2];
#pragma unroll
        for (int mt = 0; mt < 2; mt++)
          pf[mt] = *(const bf16x8*)(&myP[(mt * 16 + l15) * LDP + ks2 * 32 + quad * 8]);
#pragma unroll
        for (int dt = 0; dt < 4; dt++) {
          bf16x8 vf = *(const bf16x8*)(&Vs[(dt * 16 + l15) * 64 + (((ks2 * 4 + quad) ^ x7) * 8)]);
#pragma unroll
          for (int mt = 0; mt < 2; mt++)
            o[mt][dt] = __builtin_amdgcn_mfma_f32_16x16x32_bf16(pf[mt], vf, o[mt][dt], 0, 0, 0);
        }
      }
    }
    __syncthreads();
  }

  // epilogue: reduce row sums across 16-lane col groups, normalize, store
#pragma unroll
  for (int mt = 0; mt < 2; mt++)
#pragma unroll
    for (int r = 0; r < 4; r++) {
      float v = lsum[mt][r];
#pragma unroll
      for (int off = 1; off < 16; off <<= 1) v += __shfl_xor(v, off, 64);
      float rl = 1.0f / v;
      int t = q0w + mt * 16 + quad * 4 + r;
#pragma unroll
      for (int dt = 0; dt < 4; dt++)
        AO[((size_t)(b * T_ + t)) * C_ + h * DH_ + dt * 16 + l15] = f2b(o[mt][dt][r] * rl);
    }
}

extern "C" void kernel_launch(void* const* d_in, const int* in_sizes, int n_in,
                              void* d_out, int out_size, void* d_ws, size_t ws_size,
                              hipStream_t stream) {
  (void)in_sizes; (void)n_in; (void)out_size; (void)ws_size;
  const float* x  = (const float*)d_in[0];
  const float* Wq = (const float*)d_in[1];
  // d_in[2] = W_k unused (reference bug: K uses W_q)
  const float* Wv = (const float*)d_in[3];
  const float* Wo = (const float*)d_in[4];

  // workspace (u16 elems); AO reuses Xb slot (dead after gemm1)
  u16* Xb  = (u16*)d_ws;            // 8388608 : x bf16; later AO [B,T,C]
  u16* AOw = Xb;
  u16* Wqb = Xb  + 8388608;         // 1048576
  u16* Wvb = Wqb + 1048576;         // 1048576 (adjacent -> fused N=2048 GEMM)
  u16* Wob = Wvb + 1048576;         // 1048576
  u16* Qw  = Wob + 1048576;         // 8388608 : Q [B,H,T,Dh]
  u16* Vtw = Qw  + 8388608;         // 8388608 : Vt [B,H,Dh,T] (gemm1 writes directly)
  // total 54,525,952 bytes

  cast_all_kernel<<<11264, 256, 0, stream>>>(x, Wq, Wv, Wo, Xb, Wqb, Wvb, Wob);

  // fused Q+V projection; V half written pre-transposed (Vt base = Qw + 8388608)
  gemm_bt_kernel<<<dim3(64, 16), 256, 0, stream>>>(Xb, Wqb, (void*)Qw, 0);

  attn_kernel<<<1024, 256, 0, stream>>>(Qw, Vtw, AOw);

  gemm_bt_kernel<<<dim3(64, 8), 256, 0, stream>>>(AOw, Wob, d_out, 1);
}

// Round 7
// 222.516 us; speedup vs baseline: 1.4334x; 1.0563x over previous
//
#include <hip/hip_runtime.h>
#include <hip/hip_bf16.h>
#include <type_traits>

typedef unsigned short u16;
typedef __attribute__((ext_vector_type(8))) short bf16x8;
typedef __attribute__((ext_vector_type(4))) float f32x4;

#define B_  4
#define T_  2048
#define C_  1024
#define H_  16
#define DH_ 64
#define M_  (B_*T_)   // 8192

// async global->LDS, 16B per lane; LDS dest = wave-uniform base + lane*16
#define GLDS16(g, l) __builtin_amdgcn_global_load_lds( \
    (const __attribute__((address_space(1))) void*)(g), \
    (__attribute__((address_space(3))) void*)(l), 16, 0, 0)

__device__ __forceinline__ u16 f2b(float f) {
  union { __hip_bfloat16 h; u16 u; } cv;
  cv.h = __float2bfloat16(f);
  return cv.u;
}

// ---------------- all fp32 -> bf16 casts in one launch ----------------
__global__ void cast_all_kernel(const float* __restrict__ x,  const float* __restrict__ w0,
                                const float* __restrict__ w1, const float* __restrict__ w2,
                                u16* __restrict__ xo, u16* __restrict__ o0,
                                u16* __restrict__ o1, u16* __restrict__ o2) {
  int bid = blockIdx.x;
  const float* src; u16* dst; int blk;
  if (bid < 8192) { src = x; dst = xo; blk = bid; }
  else {
    int k = bid - 8192, w = k >> 10;
    src = (w == 0) ? w0 : (w == 1) ? w1 : w2;
    dst = (w == 0) ? o0 : (w == 1) ? o1 : o2;
    blk = k & 1023;
  }
  int i = (blk * 256 + threadIdx.x) * 4;
  float4 v = *(const float4*)(src + i);
  unsigned lo = (unsigned)f2b(v.x) | ((unsigned)f2b(v.y) << 16);
  unsigned hi = (unsigned)f2b(v.z) | ((unsigned)f2b(v.w) << 16);
  uint2 p; p.x = lo; p.y = hi;
  *(uint2*)(dst + i) = p;
}

// ---------------- GEMM (4-wave): C[m,n] = sum_k A[m,k]*B[n,k], 128x128, BK=64 ----------------
// XOR-swizzled LDS; mode 0: bf16 scatter (Q half -> [B,H,T,Dh], V half -> Vt [B,H,Dh,T])
__global__ __launch_bounds__(256) void gemm_bt_kernel(
    const u16* __restrict__ A, const u16* __restrict__ Bm,
    void* __restrict__ Cout, int mode)
{
  constexpr int K = 1024;
  __shared__ __align__(16) u16 As[128 * 64];
  __shared__ __align__(16) u16 Bs[128 * 64];

  const int tid  = threadIdx.x;
  const int wave = tid >> 6, lane = tid & 63;
  const int quad = lane >> 4, l15 = lane & 15;
  const int x7   = l15 & 7;
  const int wm = (wave >> 1) * 64, wn = (wave & 1) * 64;
  const int tm = blockIdx.x * 128, tn = blockIdx.y * 128;

  f32x4 acc[4][4] = {};

  for (int k0 = 0; k0 < K; k0 += 64) {
#pragma unroll
    for (int it = 0; it < 4; it++) {
      int ch  = it * 256 + tid;
      int row = ch >> 3;
      int cc  = (ch & 7) ^ (row & 7);
      GLDS16(A  + (size_t)(tm + row) * K + k0 + cc * 8, &As[(it * 256 + wave * 64) * 8]);
      GLDS16(Bm + (size_t)(tn + row) * K + k0 + cc * 8, &Bs[(it * 256 + wave * 64) * 8]);
    }
    __syncthreads();

#pragma unroll
    for (int ks = 0; ks < 2; ks++) {
      bf16x8 af[4], bfr[4];
#pragma unroll
      for (int t = 0; t < 4; t++) {
        int co = ((ks * 4 + quad) ^ x7) * 8;
        af[t]  = *(const bf16x8*)(&As[(wm + t * 16 + l15) * 64 + co]);
        bfr[t] = *(const bf16x8*)(&Bs[(wn + t * 16 + l15) * 64 + co]);
      }
#pragma unroll
      for (int mt = 0; mt < 4; mt++)
#pragma unroll
        for (int nt = 0; nt < 4; nt++)
          acc[mt][nt] = __builtin_amdgcn_mfma_f32_16x16x32_bf16(af[mt], bfr[nt], acc[mt][nt], 0, 0, 0);
    }
    __syncthreads();
  }

  if (mode == 0) {
    u16* out = (u16*)Cout;
    if (tn < 1024) {
#pragma unroll
      for (int mt = 0; mt < 4; mt++)
#pragma unroll
        for (int nt = 0; nt < 4; nt++)
#pragma unroll
          for (int r = 0; r < 4; r++) {
            int gm = tm + wm + mt * 16 + quad * 4 + r;
            int gn = tn + wn + nt * 16 + l15;
            int b = gm >> 11, t = gm & 2047;
            int h = gn >> 6, d = gn & 63;
            out[((size_t)((b * 16 + h) * 2048 + t) << 6) + d] = f2b(acc[mt][nt][r]);
          }
    } else {
      // V half -> Vt [B,H,Dh,T] (fused transpose)
#pragma unroll
      for (int mt = 0; mt < 4; mt++)
#pragma unroll
        for (int nt = 0; nt < 4; nt++) {
          int gm0 = tm + wm + mt * 16 + quad * 4;
          int gn  = tn - 1024 + wn + nt * 16 + l15;
          int b = gm0 >> 11, t0 = gm0 & 2047;
          int h = gn >> 6, d = gn & 63;
          alignas(8) u16 tmp[4];
#pragma unroll
          for (int r = 0; r < 4; r++) tmp[r] = f2b(acc[mt][nt][r]);
          *(ushort4*)(out + 8388608 + (((size_t)(b * 16 + h) * 64 + d) << 11) + t0)
              = *(const ushort4*)tmp;
        }
    }
  } else {
    float* out = (float*)Cout;
#pragma unroll
    for (int mt = 0; mt < 4; mt++)
#pragma unroll
      for (int nt = 0; nt < 4; nt++)
#pragma unroll
        for (int r = 0; r < 4; r++) {
          int gm = tm + wm + mt * 16 + quad * 4 + r;
          int gn = tn + wn + nt * 16 + l15;
          out[(size_t)gm * 1024 + gn] = acc[mt][nt][r];
        }
  }
}

// ---------------- GEMM (8-wave, fp32 out): 128x128 tile, 512 threads ----------------
// Same structure, doubled waves/CU (16) to hide the staging barrier drain at grid=512.
__global__ __launch_bounds__(512, 4) void gemm_bt512_kernel(
    const u16* __restrict__ A, const u16* __restrict__ Bm, float* __restrict__ out)
{
  constexpr int K = 1024;
  __shared__ __align__(16) u16 As[128 * 64];
  __shared__ __align__(16) u16 Bs[128 * 64];

  const int tid  = threadIdx.x;
  const int wave = tid >> 6, lane = tid & 63;   // wave 0..7
  const int quad = lane >> 4, l15 = lane & 15;
  const int x7   = l15 & 7;
  const int wm = (wave >> 1) * 32, wn = (wave & 1) * 64;
  const int tm = blockIdx.x * 128, tn = blockIdx.y * 128;

  f32x4 acc[2][4] = {};

  for (int k0 = 0; k0 < K; k0 += 64) {
#pragma unroll
    for (int it = 0; it < 2; it++) {
      int ch  = it * 512 + tid;
      int row = ch >> 3;
      int cc  = (ch & 7) ^ (row & 7);
      GLDS16(A  + (size_t)(tm + row) * K + k0 + cc * 8, &As[(it * 512 + wave * 64) * 8]);
      GLDS16(Bm + (size_t)(tn + row) * K + k0 + cc * 8, &Bs[(it * 512 + wave * 64) * 8]);
    }
    __syncthreads();

#pragma unroll
    for (int ks = 0; ks < 2; ks++) {
      bf16x8 af[2], bfr[4];
      int co = ((ks * 4 + quad) ^ x7) * 8;
#pragma unroll
      for (int t = 0; t < 2; t++)
        af[t]  = *(const bf16x8*)(&As[(wm + t * 16 + l15) * 64 + co]);
#pragma unroll
      for (int t = 0; t < 4; t++)
        bfr[t] = *(const bf16x8*)(&Bs[(wn + t * 16 + l15) * 64 + co]);
#pragma unroll
      for (int mt = 0; mt < 2; mt++)
#pragma unroll
        for (int nt = 0; nt < 4; nt++)
          acc[mt][nt] = __builtin_amdgcn_mfma_f32_16x16x32_bf16(af[mt], bfr[nt], acc[mt][nt], 0, 0, 0);
    }
    __syncthreads();
  }

#pragma unroll
  for (int mt = 0; mt < 2; mt++)
#pragma unroll
    for (int nt = 0; nt < 4; nt++)
#pragma unroll
      for (int r = 0; r < 4; r++) {
        int gm = tm + wm + mt * 16 + quad * 4 + r;
        int gn = tn + wn + nt * 16 + l15;
        out[(size_t)gm * 1024 + gn] = acc[mt][nt][r];
      }
}

// ---------------- causal flash attention, K==Q (reference bug), bf16 MFMA ----------------
// m97-skeleton, XOR-swizzled K/Vt LDS, fixed-max softmax (raw v_exp_f32),
// lsum via ones-MFMA (rides the MFMA pipe; kills per-elem adds + epilogue shuffles),
// compile-time diag/full tile split. XCD-packed bh; LPT q-tile map.
__global__ __launch_bounds__(256, 4) void attn_kernel(
    const u16* __restrict__ Q, const u16* __restrict__ Vt, u16* __restrict__ AO)
{
  constexpr int LDP = 72;
  __shared__ __align__(16) u16 Ks[4096];        // [key 64][dh 64] swizzled, 8KB
  __shared__ __align__(16) u16 Vs[4096];        // [d 64][key 64] swizzled, 8KB
  __shared__ __align__(16) u16 Ps[4][32 * LDP]; // per-wave P, 18KB

  const int tid  = threadIdx.x;
  const int wave = tid >> 6, lane = tid & 63;
  const int quad = lane >> 4, l15 = lane & 15;
  const int x7   = l15 & 7;
  const int bid  = blockIdx.x;
  // bits 0-5: bh, XCD-packed (bid%8 -> XCD; each XCD owns 8 bh = 4MB K+V = its L2)
  const int bh = (bid & 7) * 8 + ((bid >> 3) & 7);
  const int m  = bid >> 6;                       // 0..15
  // balanced-LPT q-tile map: CU's resident set {m, m+4, m+8, m+12} sums to 68 tiles
  const int i  = (m & 4) ? ((m & 8) ? m - 12 : m + 4) : 15 - m;
  const int b = bh >> 4, h = bh & 15;
  const u16* Qbh = Q  + (size_t)bh * (T_ * DH_);
  const u16* Vbh = Vt + (size_t)bh * (DH_ * T_);
  const int q0w = i * 128 + wave * 32;     // wave's first q-row
  const int kbd = (q0w + 31) >> 6;         // wave's diagonal k-tile
  const int nkb = 2 * i + 2;               // block-level k-tiles (64 keys each)
  u16* myP = &Ps[wave][0];

  const float C1 = 0.18033688f;    // log2(e)/sqrt(64)
  const float C2 = -28.8539008f;   // -20*log2(e)  (fixed max M=20, shift-invariant)
  const bf16x8 ones = { 0x3F80, 0x3F80, 0x3F80, 0x3F80, 0x3F80, 0x3F80, 0x3F80, 0x3F80 };

  // Q fragments: once per block, direct global
  bf16x8 qf[2][2];
#pragma unroll
  for (int mt = 0; mt < 2; mt++)
#pragma unroll
    for (int ks = 0; ks < 2; ks++)
      qf[mt][ks] = *(const bf16x8*)(Qbh + (size_t)(q0w + mt * 16 + l15) * DH_ + ks * 32 + quad * 8);

  f32x4 o[2][4] = {};
  f32x4 lsumv[2] = {};

  auto tilecomp = [&](int kb, auto DIAGC) {
    constexpr bool DIAG = decltype(DIAGC)::value;
    const int k0 = kb * 64;
    // S = Q K^T
    f32x4 s[2][4] = {};
#pragma unroll
    for (int ks = 0; ks < 2; ks++)
#pragma unroll
      for (int nt = 0; nt < 4; nt++) {
        bf16x8 kf = *(const bf16x8*)(&Ks[(nt * 16 + l15) * 64 + (((ks * 4 + quad) ^ x7) * 8)]);
#pragma unroll
        for (int mt = 0; mt < 2; mt++)
          s[mt][nt] = __builtin_amdgcn_mfma_f32_16x16x32_bf16(qf[mt][ks], kf, s[mt][nt], 0, 0, 0);
      }

    // fixed-max softmax: p = exp2(s*C1 + C2), raw v_exp_f32; store to P (bf16)
#pragma unroll
    for (int mt = 0; mt < 2; mt++)
#pragma unroll
      for (int nt = 0; nt < 4; nt++)
#pragma unroll
        for (int r = 0; r < 4; r++) {
          float p = __builtin_amdgcn_exp2f(s[mt][nt][r] * C1 + C2);
          if constexpr (DIAG) {
            int qg = q0w + mt * 16 + quad * 4 + r;
            int kg = k0 + nt * 16 + l15;
            p = (kg <= qg) ? p : 0.0f;
          }
          myP[(mt * 16 + quad * 4 + r) * LDP + nt * 16 + l15] = f2b(p);
        }

    // O += P V; row-sums via ones-MFMA (D[m][n] = sum_k P[m][k], all cols identical)
#pragma unroll
    for (int ks2 = 0; ks2 < 2; ks2++) {
      bf16x8 pf[2];
#pragma unroll
      for (int mt = 0; mt < 2; mt++) {
        pf[mt] = *(const bf16x8*)(&myP[(mt * 16 + l15) * LDP + ks2 * 32 + quad * 8]);
        lsumv[mt] = __builtin_amdgcn_mfma_f32_16x16x32_bf16(pf[mt], ones, lsumv[mt], 0, 0, 0);
      }
#pragma unroll
      for (int dt = 0; dt < 4; dt++) {
        bf16x8 vf = *(const bf16x8*)(&Vs[(dt * 16 + l15) * 64 + (((ks2 * 4 + quad) ^ x7) * 8)]);
#pragma unroll
        for (int mt = 0; mt < 2; mt++)
          o[mt][dt] = __builtin_amdgcn_mfma_f32_16x16x32_bf16(pf[mt], vf, o[mt][dt], 0, 0, 0);
      }
    }
  };

  for (int kb = 0; kb < nkb; kb++) {
    const int k0 = kb * 64;
    // stage K-tile [key][dh] and Vt-tile [d][key], fetch-side swizzle
#pragma unroll
    for (int it = 0; it < 2; it++) {
      int ch  = it * 256 + tid;
      int row = ch >> 3;
      int cc  = (ch & 7) ^ (row & 7);
      GLDS16(Qbh + (size_t)(k0 + row) * DH_ + cc * 8, &Ks[(it * 256 + wave * 64) * 8]);
      GLDS16(Vbh + (size_t)row * T_ + k0 + cc * 8,    &Vs[(it * 256 + wave * 64) * 8]);
    }
    __syncthreads();

    if (kb < kbd)        tilecomp(kb, std::false_type{});
    else if (kb == kbd)  tilecomp(kb, std::true_type{});
    __syncthreads();
  }

  // epilogue: lsumv already holds full row sums (identical across the 16-lane col group)
#pragma unroll
  for (int mt = 0; mt < 2; mt++)
#pragma unroll
    for (int r = 0; r < 4; r++) {
      float rl = 1.0f / lsumv[mt][r];
      int t = q0w + mt * 16 + quad * 4 + r;
#pragma unroll
      for (int dt = 0; dt < 4; dt++)
        AO[((size_t)(b * T_ + t)) * C_ + h * DH_ + dt * 16 + l15] = f2b(o[mt][dt][r] * rl);
    }
}

extern "C" void kernel_launch(void* const* d_in, const int* in_sizes, int n_in,
                              void* d_out, int out_size, void* d_ws, size_t ws_size,
                              hipStream_t stream) {
  (void)in_sizes; (void)n_in; (void)out_size; (void)ws_size;
  const float* x  = (const float*)d_in[0];
  const float* Wq = (const float*)d_in[1];
  // d_in[2] = W_k unused (reference bug: K uses W_q)
  const float* Wv = (const float*)d_in[3];
  const float* Wo = (const float*)d_in[4];

  // workspace (u16 elems); AO reuses Xb slot (dead after gemm1)
  u16* Xb  = (u16*)d_ws;            // 8388608 : x bf16; later AO [B,T,C]
  u16* AOw = Xb;
  u16* Wqb = Xb  + 8388608;         // 1048576
  u16* Wvb = Wqb + 1048576;         // 1048576 (adjacent -> fused N=2048 GEMM)
  u16* Wob = Wvb + 1048576;         // 1048576
  u16* Qw  = Wob + 1048576;         // 8388608 : Q [B,H,T,Dh]
  u16* Vtw = Qw  + 8388608;         // 8388608 : Vt [B,H,Dh,T] (gemm1 writes directly)
  // total 54,525,952 bytes

  cast_all_kernel<<<11264, 256, 0, stream>>>(x, Wq, Wv, Wo, Xb, Wqb, Wvb, Wob);

  // fused Q+V projection; V half written pre-transposed (Vt base = Qw + 8388608)
  gemm_bt_kernel<<<dim3(64, 16), 256, 0, stream>>>(Xb, Wqb, (void*)Qw, 0);

  attn_kernel<<<1024, 256, 0, stream>>>(Qw, Vtw, AOw);

  gemm_bt512_kernel<<<dim3(64, 8), 512, 0, stream>>>(AOw, Wob, (float*)d_out);
}